// Round 8
// baseline (242.449 us; speedup 1.0000x reference)
//
#include <hip/hip_runtime.h>

#define NTOK   8192
#define DMODEL 1024
#define NC     64
#define NK     16
#define NP     64
#define NM     128
#define LCAP   (1 << 18)
#define MARGIN 2e-3f

typedef _Float16 f16x8  __attribute__((ext_vector_type(8)));
typedef float    f32x16 __attribute__((ext_vector_type(16)));

#define AS1 __attribute__((address_space(1)))
#define AS3 __attribute__((address_space(3)))

__device__ __forceinline__ void glds16(const void* g, void* l) {
    __builtin_amdgcn_global_load_lds((const AS1 void*)g, (AS3 void*)l, 16, 0, 0);
}

// ------------------------------------------------------------------
// Kernel 0: split x, W_A, W_B into fp16 hi/lo with subtiled layout
// [k/8][row][8] so the GEMM stages via linear global_load_lds.
// hi = f16(v), lo = f16(v - hi): combined ~22-bit mantissa.
// ------------------------------------------------------------------
__global__ __launch_bounds__(256) void k_split(
    const float* __restrict__ x, const float* __restrict__ W_A, const float* __restrict__ W_B,
    short* __restrict__ xh, short* __restrict__ xl,
    short* __restrict__ whA, short* __restrict__ wlA,
    short* __restrict__ whB, short* __restrict__ wlB)
{
    const int t = blockIdx.x * 256 + threadIdx.x;
    const int NX = 128 * NTOK;            // 1048576 units
    const int NW = 128 * 1024;            // 131072 units

    const float* src;
    short *dh, *dl;
    if (t < NX) {
        const int chunk = t >> 13, tok = t & 8191;
        src = x + (size_t)tok * DMODEL + chunk * 8;
        dh = xh + (size_t)t * 8;  dl = xl + (size_t)t * 8;
    } else if (t < NX + NW) {
        const int u = t - NX, chunk = u >> 10, ck = u & 1023;
        src = W_A + (size_t)ck * DMODEL + chunk * 8;
        dh = whA + (size_t)u * 8; dl = wlA + (size_t)u * 8;
    } else {
        const int u = t - NX - NW, chunk = u >> 10, ck = u & 1023;
        src = W_B + (size_t)ck * DMODEL + chunk * 8;
        dh = whB + (size_t)u * 8; dl = wlB + (size_t)u * 8;
    }

    const float4 a = *(const float4*)src;
    const float4 b = *(const float4*)(src + 4);
    const float v[8] = {a.x, a.y, a.z, a.w, b.x, b.y, b.z, b.w};
    unsigned h[8], l[8];
    #pragma unroll
    for (int j = 0; j < 8; ++j) {
        const _Float16 hf = (_Float16)v[j];
        const _Float16 lf = (_Float16)(v[j] - (float)hf);
        h[j] = (unsigned)__builtin_bit_cast(unsigned short, hf);
        l[j] = (unsigned)__builtin_bit_cast(unsigned short, lf);
    }
    *(int4*)dh = make_int4((int)(h[0] | (h[1] << 16)), (int)(h[2] | (h[3] << 16)),
                           (int)(h[4] | (h[5] << 16)), (int)(h[6] | (h[7] << 16)));
    *(int4*)dl = make_int4((int)(l[0] | (l[1] << 16)), (int)(l[2] | (l[3] << 16)),
                           (int)(l[4] | (l[5] << 16)), (int)(l[6] | (l[7] << 16)));
}

// ------------------------------------------------------------------
// Kernel 1: fp16x3 MFMA GEMM (xh*wh + xh*wl + xl*wh) + d2 + argmin.
// 256x256 tile, 8 waves (2M x 4N), 32x32x16 MFMA, wave tile 128x64.
// BK=16 K-tiles, FOUR 32KB LDS buffers, prefetch depth 3:
//   per tile: vmcnt(8) [counted, never 0] -> 1 barrier ->
//   12 ds_read -> STAGE(t+3) -> lgkmcnt(0)+sched_barrier ->
//   setprio(1) -> 24 MFMA -> setprio(0).
// Tail re-stages tile 63 into dead buffers so vmcnt(8) stays exact.
// ------------------------------------------------------------------
__global__ __launch_bounds__(512, 1) void k_mfma_argmin(
    const short* __restrict__ xh, const short* __restrict__ xl,
    const short* __restrict__ whA, const short* __restrict__ wlA,
    const short* __restrict__ whB, const short* __restrict__ wlB,
    const float* __restrict__ emb_A, const float* __restrict__ emb_B,
    int* __restrict__ idxbuf, int* __restrict__ list, int* __restrict__ cnt)
{
    __shared__ __align__(16) float smem[32768];   // 128 KB
    short* ls = (short*)smem;
    // buf b (shorts, base b*16384): Ah +0, Al +4096, Bh +8192, Bl +12288
    float* projT = smem;                   // [256 cols][65] = 16640 floats
    float* embS  = smem + 16640;           // [8 cb][64 p][16 k] = 8192 floats
    float* e2S   = smem + 24832;           // [512]

    const int tid = threadIdx.x;
    const int bid = blockIdx.x;
    const int swz = (bid & 7) * 32 + (bid >> 3);
    const int tb  = swz >> 3;              // token block 0..31 (256 tokens)
    const int ot  = swz & 7;               // out tile 0..7 (256 cols)
    const int set = ot >> 2;
    const short* __restrict__ wh = set ? whB : whA;
    const short* __restrict__ wl = set ? wlB : wlA;
    const float* __restrict__ Ep = set ? emb_B : emb_A;
    const int ckbase = (ot & 3) * 256;     // 16 codebooks x 16 k

    const int lane = tid & 63;
    const int wid  = tid >> 6;
    const int wr   = wid >> 2;             // M half 0..1 (128 tokens)
    const int wc   = wid & 3;              // N quarter 0..3 (64 cols)
    const int lr31 = lane & 31;
    const int lk2  = lane >> 5;

    f32x16 acc[4][2];
    #pragma unroll
    for (int m = 0; m < 4; ++m)
        #pragma unroll
        for (int n = 0; n < 2; ++n)
            #pragma unroll
            for (int r = 0; r < 16; ++r) acc[m][n][r] = 0.f;

    // staging: per tile 4 glds16/thread. unit: chunk = tid>>8 (0..1), row = tid&255
    const size_t oA = ((size_t)(tid >> 8) * NTOK + tb * 256 + (tid & 255)) * 8;
    const size_t oB = ((size_t)(tid >> 8) * 1024 + ckbase + (tid & 255)) * 8;

    #define STAGE(buf, st)                                                   \
        do {                                                                 \
            const size_t sa_ = (size_t)(st) * (size_t)(2 * NTOK * 8);        \
            const size_t sb_ = (size_t)(st) * (size_t)(2 * 1024 * 8);        \
            short* lb_ = ls + (buf) * 16384 + tid * 8;                       \
            glds16(xh + oA + sa_, lb_);                                      \
            glds16(xl + oA + sa_, lb_ + 4096);                               \
            glds16(wh + oB + sb_, lb_ + 8192);                               \
            glds16(wl + oB + sb_, lb_ + 12288);                              \
        } while (0)

    // fragment LDS offsets (shorts)
    const int aoff = (lk2 * 256 + wr * 128 + lr31) * 8;
    const int boff = 8192 + (lk2 * 256 + wc * 64 + lr31) * 8;

    // prologue: 3 tiles in flight
    STAGE(0, 0);
    STAGE(1, 1);
    STAGE(2, 2);

    for (int t = 0; t < 64; ++t) {
        // counted wait: 8 outstanding allowed (tiles t+1, t+2) -> tile t landed
        asm volatile("s_waitcnt vmcnt(8)" ::: "memory");
        __builtin_amdgcn_s_barrier();

        const short* bb = ls + (t & 3) * 16384;
        f16x8 ah[4], al[4], bh[2], bl[2];
        #pragma unroll
        for (int m = 0; m < 4; ++m) {
            ah[m] = *(const f16x8*)(bb + aoff + m * 256);
            al[m] = *(const f16x8*)(bb + 4096 + aoff + m * 256);
        }
        #pragma unroll
        for (int n = 0; n < 2; ++n) {
            bh[n] = *(const f16x8*)(bb + boff + n * 256);
            bl[n] = *(const f16x8*)(bb + 8192 - 8192 + 12288 - 12288 + 4096 + boff + n * 256);
        }

        // stage tile t+3 (clamped tail keeps 3 tiles in flight; dead-buffer writes)
        {
            const int ts = (t + 3 < 64) ? (t + 3) : 63;
            STAGE((t + 3) & 3, ts);
        }

        asm volatile("s_waitcnt lgkmcnt(0)" ::: "memory");
        __builtin_amdgcn_sched_barrier(0);
        __builtin_amdgcn_s_setprio(1);
        #pragma unroll
        for (int m = 0; m < 4; ++m)
            #pragma unroll
            for (int n = 0; n < 2; ++n) {
                acc[m][n] = __builtin_amdgcn_mfma_f32_32x32x16_f16(ah[m], bh[n], acc[m][n], 0, 0, 0);
                acc[m][n] = __builtin_amdgcn_mfma_f32_32x32x16_f16(ah[m], bl[n], acc[m][n], 0, 0, 0);
                acc[m][n] = __builtin_amdgcn_mfma_f32_32x32x16_f16(al[m], bh[n], acc[m][n], 0, 0, 0);
            }
        __builtin_amdgcn_s_setprio(0);
    }
    #undef STAGE

    // drain outstanding (redundant tail) loads before smem reuse
    asm volatile("s_waitcnt vmcnt(0)" ::: "memory");
    __builtin_amdgcn_s_barrier();

    // ---- epilogue ----
    // acc[m][n][r] = proj[row = wr*128 + m*32 + (r&3)+8*(r>>2)+4*lk2]
    //                    [col = wc*64 + n*32 + lr31]
    #pragma unroll
    for (int ch = 0; ch < 2; ++ch) {
        __syncthreads();
        {   // stage 8 codebooks of emb: 8192 floats
            const float4* eg = (const float4*)(Ep + (size_t)((ot & 3) * 16 + ch * 8) * NP * NK);
            float4* es = (float4*)embS;
            #pragma unroll
            for (int i = 0; i < 4; ++i) es[tid + 512 * i] = eg[tid + 512 * i];
        }
        __syncthreads();
        {   // e2 per (cb_local, p)
            const float* e = embS + tid * 16;
            float s = 0.f;
            #pragma unroll
            for (int k = 0; k < 16; ++k) s = fmaf(e[k], e[k], s);
            e2S[tid] = s;
        }
        #pragma unroll
        for (int c = 0; c < 4; ++c) {
            __syncthreads();
            if (wr == (c >> 1)) {   // this wave-half owns chunk c's 64 rows
                #pragma unroll
                for (int mi = 0; mi < 2; ++mi) {
                    const int m = (c & 1) * 2 + mi;
                    #pragma unroll
                    for (int n = 0; n < 2; ++n) {
                        const int col = wc * 64 + n * 32 + lr31;
                        #pragma unroll
                        for (int r = 0; r < 16; ++r) {
                            const int trow = mi * 32 + (r & 3) + 8 * (r >> 2) + 4 * lk2;
                            projT[col * 65 + trow] = acc[m][n][r];
                        }
                    }
                }
            }
            __syncthreads();
            {   // argmin: one task per thread: token lt of chunk, codebook cbl
                const int lt = tid & 63, cbl = tid >> 6;      // cbl 0..7
                float pr[16];
                #pragma unroll
                for (int k = 0; k < 16; ++k)
                    pr[k] = projT[((ch * 8 + cbl) * 16 + k) * 65 + lt];
                const float4* eb4 = (const float4*)(embS + cbl * 1024);
                const float* e2 = e2S + cbl * 64;
                float best = 1e30f, second = 1e30f;
                int bp = 0;
                for (int p = 0; p < 64; ++p) {
                    const float4 e0 = eb4[p * 4 + 0], e1 = eb4[p * 4 + 1];
                    const float4 e2v = eb4[p * 4 + 2], e3 = eb4[p * 4 + 3];
                    float s = 0.f;
                    s = fmaf(pr[0], e0.x, s);   s = fmaf(pr[1], e0.y, s);
                    s = fmaf(pr[2], e0.z, s);   s = fmaf(pr[3], e0.w, s);
                    s = fmaf(pr[4], e1.x, s);   s = fmaf(pr[5], e1.y, s);
                    s = fmaf(pr[6], e1.z, s);   s = fmaf(pr[7], e1.w, s);
                    s = fmaf(pr[8], e2v.x, s);  s = fmaf(pr[9], e2v.y, s);
                    s = fmaf(pr[10], e2v.z, s); s = fmaf(pr[11], e2v.w, s);
                    s = fmaf(pr[12], e3.x, s);  s = fmaf(pr[13], e3.y, s);
                    s = fmaf(pr[14], e3.z, s);  s = fmaf(pr[15], e3.w, s);
                    const float g = fmaf(-2.f, s, e2[p]);
                    if (g < best) { second = best; best = g; bp = p; }
                    else if (g < second) { second = g; }
                }
                const int cbook = (ot & 3) * 16 + ch * 8 + cbl;
                const int gtok = tb * 256 + c * 64 + lt;
                idxbuf[(set * NC + cbook) * NTOK + gtok] = bp;
                if (second - best < MARGIN) {
                    const int slot = atomicAdd(cnt, 1);
                    if (slot < LCAP) list[slot] = (set << 19) | (cbook << 13) | gtok;
                }
            }
        }
    }
}

// ------------------------------------------------------------------
// Kernel 2: fp64 exact re-resolution of flagged near-tie argmins.
// ------------------------------------------------------------------
__global__ __launch_bounds__(256) void k_refine(
    const float* __restrict__ x,
    const float* __restrict__ W_A, const float* __restrict__ W_B,
    const float* __restrict__ emb_A, const float* __restrict__ emb_B,
    const int* __restrict__ list, const int* __restrict__ cnt,
    int* __restrict__ idxbuf)
{
    int n = *cnt;
    if (n > LCAP) n = LCAP;
    const int lane = threadIdx.x & 63;
    const int wave = (int)((blockIdx.x * blockDim.x + threadIdx.x) >> 6);
    const int nw   = (int)((gridDim.x * blockDim.x) >> 6);

    for (int i = wave; i < n; i += nw) {
        const int code = list[i];
        const int tok = code & 8191;
        const int c   = (code >> 13) & 63;
        const int set = (code >> 19) & 1;
        const float* __restrict__ Wp = set ? W_B : W_A;
        const float* __restrict__ Ep = set ? emb_B : emb_A;

        double pk[16];
        #pragma unroll
        for (int k = 0; k < 16; ++k) pk[k] = 0.0;
        for (int dd = 0; dd < 16; ++dd) {
            const int d = dd * 64 + lane;
            const double xv = (double)x[(size_t)tok * DMODEL + d];
            #pragma unroll
            for (int k = 0; k < 16; ++k)
                pk[k] = fma(xv, (double)Wp[(size_t)(c * 16 + k) * DMODEL + d], pk[k]);
        }
        #pragma unroll
        for (int k = 0; k < 16; ++k) {
            #pragma unroll
            for (int off = 32; off; off >>= 1)
                pk[k] += __shfl_xor(pk[k], off, 64);
        }
        double d2 = 0.0;
        #pragma unroll
        for (int k = 0; k < 16; ++k) {
            const double t = pk[k] - (double)Ep[(size_t)(c * NP + lane) * NK + k];
            d2 = fma(t, t, d2);
        }
        int bp = lane;
        double bv = d2;
        #pragma unroll
        for (int off = 32; off; off >>= 1) {
            const double ov = __shfl_xor(bv, off, 64);
            const int    op = __shfl_xor(bp, off, 64);
            if (ov < bv || (ov == bv && op < bp)) { bv = ov; bp = op; }
        }
        if (lane == 0) idxbuf[(set * NC + c) * NTOK + tok] = bp;
    }
}

// ------------------------------------------------------------------
// Kernel 3: per-token gather + t[r] + out[d]. One block per token.
// ------------------------------------------------------------------
__global__ __launch_bounds__(256) void k_combine(
    const float* __restrict__ x,
    const float* __restrict__ vals_A, const float* __restrict__ vals_B,
    const int* __restrict__ idxbuf, float* __restrict__ out)
{
    __shared__ float xsh[1032];
    __shared__ float part[256];
    __shared__ float tsh[8];
    __shared__ int sIA[64];
    __shared__ int sIB[64];

    const int tid = threadIdx.x;
    const int tok = blockIdx.x;

    if (tid < 64) {
        sIA[tid] = idxbuf[tid * NTOK + tok];
        sIB[tid] = idxbuf[(NC + tid) * NTOK + tok];
    }
    {
        const float4 v = *(const float4*)(x + (size_t)tok * DMODEL + tid * 4);
        const int base = tid * 4 + (tid >> 5);
        xsh[base + 0] = v.x;
        xsh[base + 1] = v.y;
        xsh[base + 2] = v.z;
        xsh[base + 3] = v.w;
    }
    __syncthreads();
    {
        const int c = tid & 63, mseg = tid >> 6;
        const int ia = sIA[c];
        const float4* va = (const float4*)(vals_A + (size_t)(c * NP + ia) * NM + mseg * 32);
        const float* xb = xsh + (c & 7) * 129 + mseg * 32;
        float s = 0.f;
        #pragma unroll
        for (int i = 0; i < 8; ++i) {
            const float4 v = va[i];
            s = fmaf(v.x, xb[i * 4 + 0], s);
            s = fmaf(v.y, xb[i * 4 + 1], s);
            s = fmaf(v.z, xb[i * 4 + 2], s);
            s = fmaf(v.w, xb[i * 4 + 3], s);
        }
        part[tid] = s;
    }
    __syncthreads();
    if (tid < 8) {
        float s = 0.f;
        #pragma unroll
        for (int m = 0; m < 4; ++m)
            #pragma unroll
            for (int j = 0; j < 8; ++j)
                s += part[m * 64 + tid * 8 + j];
        tsh[tid] = s;
    }
    __syncthreads();
    {
        const int d0 = tid * 4, dblk = tid >> 5, dm = d0 & 127;
        float o0 = 0.f, o1 = 0.f, o2 = 0.f, o3 = 0.f;
        #pragma unroll
        for (int r = 0; r < 8; ++r) {
            const int cb = 8 * r + dblk;
            const int ib = sIB[cb];
            const float4 v = *(const float4*)(vals_B + (size_t)(cb * NP + ib) * NM + dm);
            const float tv = tsh[r];
            o0 = fmaf(tv, v.x, o0);
            o1 = fmaf(tv, v.y, o1);
            o2 = fmaf(tv, v.z, o2);
            o3 = fmaf(tv, v.w, o3);
        }
        *(float4*)(out + (size_t)tok * DMODEL + d0) = make_float4(o0, o1, o2, o3);
    }
}

extern "C" void kernel_launch(void* const* d_in, const int* in_sizes, int n_in,
                              void* d_out, int out_size, void* d_ws, size_t ws_size,
                              hipStream_t stream)
{
    const float* x      = (const float*)d_in[0];
    const float* W_A    = (const float*)d_in[1];
    const float* emb_A  = (const float*)d_in[2];
    const float* vals_A = (const float*)d_in[3];
    const float* W_B    = (const float*)d_in[4];
    const float* emb_B  = (const float*)d_in[5];
    const float* vals_B = (const float*)d_in[6];
    float* out = (float*)d_out;

    // ws: cnt 16B | list 1MB | idxbuf 4MB | xh 16MB | xl 16MB | whA/wlA/whB/wlB 2MB each
    char* w = (char*)d_ws;
    int*   cnt    = (int*)w;
    int*   list   = (int*)(w + 16);
    int*   idxbuf = (int*)(w + 16 + sizeof(int) * (size_t)LCAP);
    size_t off = 16 + sizeof(int) * (size_t)LCAP + sizeof(int) * (size_t)(2 * NC * NTOK);
    short* xh  = (short*)(w + off); off += (size_t)NTOK * DMODEL * 2;
    short* xl  = (short*)(w + off); off += (size_t)NTOK * DMODEL * 2;
    short* whA = (short*)(w + off); off += (size_t)1024 * DMODEL * 2;
    short* wlA = (short*)(w + off); off += (size_t)1024 * DMODEL * 2;
    short* whB = (short*)(w + off); off += (size_t)1024 * DMODEL * 2;
    short* wlB = (short*)(w + off);

    hipMemsetAsync(cnt, 0, sizeof(int), stream);
    k_split<<<5120, 256, 0, stream>>>(x, W_A, W_B, xh, xl, whA, wlA, whB, wlB);
    k_mfma_argmin<<<256, 512, 0, stream>>>(xh, xl, whA, wlA, whB, wlB,
                                           emb_A, emb_B, idxbuf, list, cnt);
    k_refine<<<1024, 256, 0, stream>>>(x, W_A, W_B, emb_A, emb_B, list, cnt, idxbuf);
    k_combine<<<NTOK, 256, 0, stream>>>(x, vals_A, vals_B, idxbuf, out);
}

// Round 9
// 240.571 us; speedup vs baseline: 1.0078x; 1.0078x over previous
//
#include <hip/hip_runtime.h>

#define NTOK   8192
#define DMODEL 1024
#define NC     64
#define NK     16
#define NP     64
#define NM     128
#define LCAP   (1 << 18)
#define MARGIN 2e-3f

typedef _Float16 f16x8  __attribute__((ext_vector_type(8)));
typedef float    f32x16 __attribute__((ext_vector_type(16)));

#define AS1 __attribute__((address_space(1)))
#define AS3 __attribute__((address_space(3)))

__device__ __forceinline__ void glds16(const void* g, void* l) {
    __builtin_amdgcn_global_load_lds((const AS1 void*)g, (AS3 void*)l, 16, 0, 0);
}

// ------------------------------------------------------------------
// Kernel 0: split x, W_A, W_B into fp16 hi/lo with subtiled layout
// [k/8][row][8] so the GEMM stages via linear global_load_lds.
// ------------------------------------------------------------------
__global__ __launch_bounds__(256) void k_split(
    const float* __restrict__ x, const float* __restrict__ W_A, const float* __restrict__ W_B,
    short* __restrict__ xh, short* __restrict__ xl,
    short* __restrict__ whA, short* __restrict__ wlA,
    short* __restrict__ whB, short* __restrict__ wlB)
{
    const int t = blockIdx.x * 256 + threadIdx.x;
    const int NX = 128 * NTOK;            // 1048576 units
    const int NW = 128 * 1024;            // 131072 units

    const float* src;
    short *dh, *dl;
    if (t < NX) {
        const int chunk = t >> 13, tok = t & 8191;
        src = x + (size_t)tok * DMODEL + chunk * 8;
        dh = xh + (size_t)t * 8;  dl = xl + (size_t)t * 8;
    } else if (t < NX + NW) {
        const int u = t - NX, chunk = u >> 10, ck = u & 1023;
        src = W_A + (size_t)ck * DMODEL + chunk * 8;
        dh = whA + (size_t)u * 8; dl = wlA + (size_t)u * 8;
    } else {
        const int u = t - NX - NW, chunk = u >> 10, ck = u & 1023;
        src = W_B + (size_t)ck * DMODEL + chunk * 8;
        dh = whB + (size_t)u * 8; dl = wlB + (size_t)u * 8;
    }

    const float4 a = *(const float4*)src;
    const float4 b = *(const float4*)(src + 4);
    const float v[8] = {a.x, a.y, a.z, a.w, b.x, b.y, b.z, b.w};
    unsigned h[8], l[8];
    #pragma unroll
    for (int j = 0; j < 8; ++j) {
        const _Float16 hf = (_Float16)v[j];
        const _Float16 lf = (_Float16)(v[j] - (float)hf);
        h[j] = (unsigned)__builtin_bit_cast(unsigned short, hf);
        l[j] = (unsigned)__builtin_bit_cast(unsigned short, lf);
    }
    *(int4*)dh = make_int4((int)(h[0] | (h[1] << 16)), (int)(h[2] | (h[3] << 16)),
                           (int)(h[4] | (h[5] << 16)), (int)(h[6] | (h[7] << 16)));
    *(int4*)dl = make_int4((int)(l[0] | (l[1] << 16)), (int)(l[2] | (l[3] << 16)),
                           (int)(l[4] | (l[5] << 16)), (int)(l[6] | (l[7] << 16)));
}

// ------------------------------------------------------------------
// Kernel 1: fp16x3 MFMA GEMM + d2 + argmin.
// 256x256 tile, 8 waves (2M x 4N), 32x32x16 MFMA, BK=16, 4 LDS bufs.
// Register-level fragment prefetch: per tile T the wave issues the 12
// ds_reads for tile T+1 and MFMAs tile T from registers -> LDS-read
// pipe drains under the MFMA cluster (true pipe overlap).
// Per tile: vmcnt(8) -> lgkm(0) [stage-safety] -> barrier ->
// reads(T+1) + STAGE(T+4) -> MFMA(T).
// ------------------------------------------------------------------
struct Frags { f16x8 ah[4], al[4], bh[2], bl[2]; };

__device__ __forceinline__ void load_frags(Frags& f, const short* bb,
                                           int aoff, int boff) {
    #pragma unroll
    for (int m = 0; m < 4; ++m) {
        f.ah[m] = *(const f16x8*)(bb + aoff + m * 256);
        f.al[m] = *(const f16x8*)(bb + 4096 + aoff + m * 256);
    }
    #pragma unroll
    for (int n = 0; n < 2; ++n) {
        f.bh[n] = *(const f16x8*)(bb + boff + n * 256);
        f.bl[n] = *(const f16x8*)(bb + 4096 + boff + n * 256);
    }
}

__device__ __forceinline__ void do_mfma(f32x16 acc[4][2], const Frags& f) {
    #pragma unroll
    for (int m = 0; m < 4; ++m)
        #pragma unroll
        for (int n = 0; n < 2; ++n)
            acc[m][n] = __builtin_amdgcn_mfma_f32_32x32x16_f16(f.ah[m], f.bh[n], acc[m][n], 0, 0, 0);
    #pragma unroll
    for (int m = 0; m < 4; ++m)
        #pragma unroll
        for (int n = 0; n < 2; ++n)
            acc[m][n] = __builtin_amdgcn_mfma_f32_32x32x16_f16(f.ah[m], f.bl[n], acc[m][n], 0, 0, 0);
    #pragma unroll
    for (int m = 0; m < 4; ++m)
        #pragma unroll
        for (int n = 0; n < 2; ++n)
            acc[m][n] = __builtin_amdgcn_mfma_f32_32x32x16_f16(f.al[m], f.bh[n], acc[m][n], 0, 0, 0);
}

__global__ __launch_bounds__(512, 1) void k_mfma_argmin(
    const short* __restrict__ xh, const short* __restrict__ xl,
    const short* __restrict__ whA, const short* __restrict__ wlA,
    const short* __restrict__ whB, const short* __restrict__ wlB,
    const float* __restrict__ emb_A, const float* __restrict__ emb_B,
    int* __restrict__ idxbuf, int* __restrict__ list, int* __restrict__ cnt)
{
    __shared__ __align__(16) float smem[32768];   // 128 KB
    short* ls = (short*)smem;
    // buf b (shorts, base b*16384): Ah +0, Al +4096, Bh +8192, Bl +12288
    float* projT = smem;                   // [256 cols][65] = 16640 floats
    float* embS  = smem + 16640;           // [8 cb][64 p][16 k] = 8192 floats
    float* e2S   = smem + 24832;           // [512]

    const int tid = threadIdx.x;
    const int bid = blockIdx.x;
    const int swz = (bid & 7) * 32 + (bid >> 3);
    const int tb  = swz >> 3;              // token block 0..31 (256 tokens)
    const int ot  = swz & 7;               // out tile 0..7 (256 cols)
    const int set = ot >> 2;
    const short* __restrict__ wh = set ? whB : whA;
    const short* __restrict__ wl = set ? wlB : wlA;
    const float* __restrict__ Ep = set ? emb_B : emb_A;
    const int ckbase = (ot & 3) * 256;     // 16 codebooks x 16 k

    const int lane = tid & 63;
    const int wid  = tid >> 6;
    const int wr   = wid >> 2;             // M half 0..1 (128 tokens)
    const int wc   = wid & 3;              // N quarter 0..3 (64 cols)
    const int lr31 = lane & 31;
    const int lk2  = lane >> 5;

    f32x16 acc[4][2];
    #pragma unroll
    for (int m = 0; m < 4; ++m)
        #pragma unroll
        for (int n = 0; n < 2; ++n)
            #pragma unroll
            for (int r = 0; r < 16; ++r) acc[m][n][r] = 0.f;

    // staging: per tile 4 glds16/thread. unit: chunk = tid>>8 (0..1), row = tid&255
    const size_t oA = ((size_t)(tid >> 8) * NTOK + tb * 256 + (tid & 255)) * 8;
    const size_t oB = ((size_t)(tid >> 8) * 1024 + ckbase + (tid & 255)) * 8;

    #define STAGE(buf, st)                                                   \
        do {                                                                 \
            const size_t sa_ = (size_t)(st) * (size_t)(2 * NTOK * 8);        \
            const size_t sb_ = (size_t)(st) * (size_t)(2 * 1024 * 8);        \
            short* lb_ = ls + (buf) * 16384 + tid * 8;                       \
            glds16(xh + oA + sa_, lb_);                                      \
            glds16(xl + oA + sa_, lb_ + 4096);                               \
            glds16(wh + oB + sb_, lb_ + 8192);                               \
            glds16(wl + oB + sb_, lb_ + 12288);                              \
        } while (0)

    // fragment LDS offsets (shorts)
    const int aoff = (lk2 * 256 + wr * 128 + lr31) * 8;
    const int boff = 8192 + (lk2 * 256 + wc * 64 + lr31) * 8;

    Frags fE, fO;

    // prologue: 4 tiles in flight, read tile-0 frags
    STAGE(0, 0);
    STAGE(1, 1);
    STAGE(2, 2);
    STAGE(3, 3);
    asm volatile("s_waitcnt vmcnt(12)" ::: "memory");
    __builtin_amdgcn_s_barrier();
    __builtin_amdgcn_sched_barrier(0);
    load_frags(fE, ls, aoff, boff);

    // BODY(T): CUR = frags(T) [in regs], NXT <- reads of tile T+1.
    //  vmcnt(8): my stage(T+1) landed.  lgkm(0): my reads(T) done.
    //  barrier: all waves' reads(T) done + stage(T+1) visible.
    //  -> issue reads(T+1), issue STAGE(T+4) into buf[T&3], MFMA(T).
    #define BODY(T, CUR, NXT)                                                \
        do {                                                                 \
            asm volatile("s_waitcnt vmcnt(8)" ::: "memory");                 \
            asm volatile("s_waitcnt lgkmcnt(0)" ::: "memory");               \
            __builtin_amdgcn_sched_barrier(0);                               \
            __builtin_amdgcn_s_barrier();                                    \
            __builtin_amdgcn_sched_barrier(0);                               \
            load_frags(NXT, ls + (((T) + 1) & 3) * 16384, aoff, boff);       \
            { const int ts_ = ((T) + 4 < 64) ? (T) + 4 : 63;                 \
              STAGE((T) & 3, ts_); }                                         \
            __builtin_amdgcn_s_setprio(1);                                   \
            do_mfma(acc, CUR);                                               \
            __builtin_amdgcn_s_setprio(0);                                   \
        } while (0)

    for (int t = 0; t < 62; t += 2) {
        BODY(t, fE, fO);
        BODY(t + 1, fO, fE);
    }
    BODY(62, fE, fO);
    // tail T=63: no further reads/stages
    asm volatile("s_waitcnt lgkmcnt(0)" ::: "memory");
    __builtin_amdgcn_sched_barrier(0);
    __builtin_amdgcn_s_barrier();
    __builtin_amdgcn_s_setprio(1);
    do_mfma(acc, fO);
    __builtin_amdgcn_s_setprio(0);
    #undef BODY
    #undef STAGE

    // drain outstanding staging loads before smem reuse
    asm volatile("s_waitcnt vmcnt(0)" ::: "memory");
    __builtin_amdgcn_s_barrier();

    // ---- epilogue ----
    // acc[m][n][r] = proj[row = wr*128 + m*32 + (r&3)+8*(r>>2)+4*lk2]
    //                    [col = wc*64 + n*32 + lr31]
    #pragma unroll
    for (int ch = 0; ch < 2; ++ch) {
        __syncthreads();
        {   // stage 8 codebooks of emb: 8192 floats
            const float4* eg = (const float4*)(Ep + (size_t)((ot & 3) * 16 + ch * 8) * NP * NK);
            float4* es = (float4*)embS;
            #pragma unroll
            for (int i = 0; i < 4; ++i) es[tid + 512 * i] = eg[tid + 512 * i];
        }
        __syncthreads();
        {   // e2 per (cb_local, p)
            const float* e = embS + tid * 16;
            float s = 0.f;
            #pragma unroll
            for (int k = 0; k < 16; ++k) s = fmaf(e[k], e[k], s);
            e2S[tid] = s;
        }
        #pragma unroll
        for (int c = 0; c < 4; ++c) {
            __syncthreads();
            if (wr == (c >> 1)) {   // this wave-half owns chunk c's 64 rows
                #pragma unroll
                for (int mi = 0; mi < 2; ++mi) {
                    const int m = (c & 1) * 2 + mi;
                    #pragma unroll
                    for (int n = 0; n < 2; ++n) {
                        const int col = wc * 64 + n * 32 + lr31;
                        #pragma unroll
                        for (int r = 0; r < 16; ++r) {
                            const int trow = mi * 32 + (r & 3) + 8 * (r >> 2) + 4 * lk2;
                            projT[col * 65 + trow] = acc[m][n][r];
                        }
                    }
                }
            }
            __syncthreads();
            {   // argmin: one task per thread: token lt of chunk, codebook cbl
                const int lt = tid & 63, cbl = tid >> 6;      // cbl 0..7
                float pr[16];
                #pragma unroll
                for (int k = 0; k < 16; ++k)
                    pr[k] = projT[((ch * 8 + cbl) * 16 + k) * 65 + lt];
                const float4* eb4 = (const float4*)(embS + cbl * 1024);
                const float* e2 = e2S + cbl * 64;
                float best = 1e30f, second = 1e30f;
                int bp = 0;
                #pragma unroll 4
                for (int p = 0; p < 64; ++p) {
                    const float4 e0 = eb4[p * 4 + 0], e1 = eb4[p * 4 + 1];
                    const float4 e2v = eb4[p * 4 + 2], e3 = eb4[p * 4 + 3];
                    float s = 0.f;
                    s = fmaf(pr[0], e0.x, s);   s = fmaf(pr[1], e0.y, s);
                    s = fmaf(pr[2], e0.z, s);   s = fmaf(pr[3], e0.w, s);
                    s = fmaf(pr[4], e1.x, s);   s = fmaf(pr[5], e1.y, s);
                    s = fmaf(pr[6], e1.z, s);   s = fmaf(pr[7], e1.w, s);
                    s = fmaf(pr[8], e2v.x, s);  s = fmaf(pr[9], e2v.y, s);
                    s = fmaf(pr[10], e2v.z, s); s = fmaf(pr[11], e2v.w, s);
                    s = fmaf(pr[12], e3.x, s);  s = fmaf(pr[13], e3.y, s);
                    s = fmaf(pr[14], e3.z, s);  s = fmaf(pr[15], e3.w, s);
                    const float g = fmaf(-2.f, s, e2[p]);
                    if (g < best) { second = best; best = g; bp = p; }
                    else if (g < second) { second = g; }
                }
                const int cbook = (ot & 3) * 16 + ch * 8 + cbl;
                const int gtok = tb * 256 + c * 64 + lt;
                idxbuf[(set * NC + cbook) * NTOK + gtok] = bp;
                if (second - best < MARGIN) {
                    const int slot = atomicAdd(cnt, 1);
                    if (slot < LCAP) list[slot] = (set << 19) | (cbook << 13) | gtok;
                }
            }
        }
    }
}

// ------------------------------------------------------------------
// Kernel 2: fp64 exact re-resolution of flagged near-tie argmins.
// ------------------------------------------------------------------
__global__ __launch_bounds__(256) void k_refine(
    const float* __restrict__ x,
    const float* __restrict__ W_A, const float* __restrict__ W_B,
    const float* __restrict__ emb_A, const float* __restrict__ emb_B,
    const int* __restrict__ list, const int* __restrict__ cnt,
    int* __restrict__ idxbuf)
{
    int n = *cnt;
    if (n > LCAP) n = LCAP;
    const int lane = threadIdx.x & 63;
    const int wave = (int)((blockIdx.x * blockDim.x + threadIdx.x) >> 6);
    const int nw   = (int)((gridDim.x * blockDim.x) >> 6);

    for (int i = wave; i < n; i += nw) {
        const int code = list[i];
        const int tok = code & 8191;
        const int c   = (code >> 13) & 63;
        const int set = (code >> 19) & 1;
        const float* __restrict__ Wp = set ? W_B : W_A;
        const float* __restrict__ Ep = set ? emb_B : emb_A;

        double pk[16];
        #pragma unroll
        for (int k = 0; k < 16; ++k) pk[k] = 0.0;
        for (int dd = 0; dd < 16; ++dd) {
            const int d = dd * 64 + lane;
            const double xv = (double)x[(size_t)tok * DMODEL + d];
            #pragma unroll
            for (int k = 0; k < 16; ++k)
                pk[k] = fma(xv, (double)Wp[(size_t)(c * 16 + k) * DMODEL + d], pk[k]);
        }
        #pragma unroll
        for (int k = 0; k < 16; ++k) {
            #pragma unroll
            for (int off = 32; off; off >>= 1)
                pk[k] += __shfl_xor(pk[k], off, 64);
        }
        double d2 = 0.0;
        #pragma unroll
        for (int k = 0; k < 16; ++k) {
            const double t = pk[k] - (double)Ep[(size_t)(c * NP + lane) * NK + k];
            d2 = fma(t, t, d2);
        }
        int bp = lane;
        double bv = d2;
        #pragma unroll
        for (int off = 32; off; off >>= 1) {
            const double ov = __shfl_xor(bv, off, 64);
            const int    op = __shfl_xor(bp, off, 64);
            if (ov < bv || (ov == bv && op < bp)) { bv = ov; bp = op; }
        }
        if (lane == 0) idxbuf[(set * NC + c) * NTOK + tok] = bp;
    }
}

// ------------------------------------------------------------------
// Kernel 3: per-token gather + t[r] + out[d]. One block per token.
// ------------------------------------------------------------------
__global__ __launch_bounds__(256) void k_combine(
    const float* __restrict__ x,
    const float* __restrict__ vals_A, const float* __restrict__ vals_B,
    const int* __restrict__ idxbuf, float* __restrict__ out)
{
    __shared__ float xsh[1032];
    __shared__ float part[256];
    __shared__ float tsh[8];
    __shared__ int sIA[64];
    __shared__ int sIB[64];

    const int tid = threadIdx.x;
    const int tok = blockIdx.x;

    if (tid < 64) {
        sIA[tid] = idxbuf[tid * NTOK + tok];
        sIB[tid] = idxbuf[(NC + tid) * NTOK + tok];
    }
    {
        const float4 v = *(const float4*)(x + (size_t)tok * DMODEL + tid * 4);
        const int base = tid * 4 + (tid >> 5);
        xsh[base + 0] = v.x;
        xsh[base + 1] = v.y;
        xsh[base + 2] = v.z;
        xsh[base + 3] = v.w;
    }
    __syncthreads();
    {
        const int c = tid & 63, mseg = tid >> 6;
        const int ia = sIA[c];
        const float4* va = (const float4*)(vals_A + (size_t)(c * NP + ia) * NM + mseg * 32);
        const float* xb = xsh + (c & 7) * 129 + mseg * 32;
        float s = 0.f;
        #pragma unroll
        for (int i = 0; i < 8; ++i) {
            const float4 v = va[i];
            s = fmaf(v.x, xb[i * 4 + 0], s);
            s = fmaf(v.y, xb[i * 4 + 1], s);
            s = fmaf(v.z, xb[i * 4 + 2], s);
            s = fmaf(v.w, xb[i * 4 + 3], s);
        }
        part[tid] = s;
    }
    __syncthreads();
    if (tid < 8) {
        float s = 0.f;
        #pragma unroll
        for (int m = 0; m < 4; ++m)
            #pragma unroll
            for (int j = 0; j < 8; ++j)
                s += part[m * 64 + tid * 8 + j];
        tsh[tid] = s;
    }
    __syncthreads();
    {
        const int d0 = tid * 4, dblk = tid >> 5, dm = d0 & 127;
        float o0 = 0.f, o1 = 0.f, o2 = 0.f, o3 = 0.f;
        #pragma unroll
        for (int r = 0; r < 8; ++r) {
            const int cb = 8 * r + dblk;
            const int ib = sIB[cb];
            const float4 v = *(const float4*)(vals_B + (size_t)(cb * NP + ib) * NM + dm);
            const float tv = tsh[r];
            o0 = fmaf(tv, v.x, o0);
            o1 = fmaf(tv, v.y, o1);
            o2 = fmaf(tv, v.z, o2);
            o3 = fmaf(tv, v.w, o3);
        }
        *(float4*)(out + (size_t)tok * DMODEL + d0) = make_float4(o0, o1, o2, o3);
    }
}

extern "C" void kernel_launch(void* const* d_in, const int* in_sizes, int n_in,
                              void* d_out, int out_size, void* d_ws, size_t ws_size,
                              hipStream_t stream)
{
    const float* x      = (const float*)d_in[0];
    const float* W_A    = (const float*)d_in[1];
    const float* emb_A  = (const float*)d_in[2];
    const float* vals_A = (const float*)d_in[3];
    const float* W_B    = (const float*)d_in[4];
    const float* emb_B  = (const float*)d_in[5];
    const float* vals_B = (const float*)d_in[6];
    float* out = (float*)d_out;

    // ws: cnt 16B | list 1MB | idxbuf 4MB | xh 16MB | xl 16MB | whA/wlA/whB/wlB 2MB each
    char* w = (char*)d_ws;
    int*   cnt    = (int*)w;
    int*   list   = (int*)(w + 16);
    int*   idxbuf = (int*)(w + 16 + sizeof(int) * (size_t)LCAP);
    size_t off = 16 + sizeof(int) * (size_t)LCAP + sizeof(int) * (size_t)(2 * NC * NTOK);
    short* xh  = (short*)(w + off); off += (size_t)NTOK * DMODEL * 2;
    short* xl  = (short*)(w + off); off += (size_t)NTOK * DMODEL * 2;
    short* whA = (short*)(w + off); off += (size_t)1024 * DMODEL * 2;
    short* wlA = (short*)(w + off); off += (size_t)1024 * DMODEL * 2;
    short* whB = (short*)(w + off); off += (size_t)1024 * DMODEL * 2;
    short* wlB = (short*)(w + off);

    hipMemsetAsync(cnt, 0, sizeof(int), stream);
    k_split<<<5120, 256, 0, stream>>>(x, W_A, W_B, xh, xl, whA, wlA, whB, wlB);
    k_mfma_argmin<<<256, 512, 0, stream>>>(xh, xl, whA, wlA, whB, wlB,
                                           emb_A, emb_B, idxbuf, list, cnt);
    k_refine<<<1024, 256, 0, stream>>>(x, W_A, W_B, emb_A, emb_B, list, cnt, idxbuf);
    k_combine<<<NTOK, 256, 0, stream>>>(x, vals_A, vals_B, idxbuf, out);
}